// Round 1
// baseline (3290.461 us; speedup 1.0000x reference)
//
#include <hip/hip_runtime.h>

#define N_NODES 50000
#define N_EDGES 800000
#define HID     128
#define NGRAPH  64
#define BN_EPS  1e-5f

// ---------------- degree / norm ----------------
__global__ __launch_bounds__(256) void deg_count_kernel(const int* __restrict__ ei,
                                                        float* __restrict__ deg) {
    int i = blockIdx.x * 256 + threadIdx.x;
    int stride = gridDim.x * 256;
    for (; i < N_EDGES; i += stride)
        atomicAdd(&deg[ei[N_EDGES + i]], 1.0f);
}

__global__ __launch_bounds__(256) void deg_fin_kernel(float* __restrict__ dinv) {
    int i = blockIdx.x * 256 + threadIdx.x;
    if (i < N_NODES) {
        float d = dinv[i] + 1.0f;   // +1 self loop
        dinv[i] = 1.0f / sqrtf(d);
    }
}

// ---------------- GEMM: h = X @ W ; agg_init = h*dinv^2 + b ----------------
// block: 256 threads, 64 rows x 128 cols of output
__global__ __launch_bounds__(256) void gemm_kernel(const float* __restrict__ X,
                                                   const float* __restrict__ W,
                                                   const float* __restrict__ bias,
                                                   const float* __restrict__ dinv,
                                                   float* __restrict__ hout,
                                                   float* __restrict__ aggout) {
    __shared__ float xs[64][128];
    const int tid = threadIdx.x;
    const int block_row = blockIdx.x * 64;

    // stage X tile (float4-coalesced)
    {
        const float4* Xv = (const float4*)(X + (size_t)block_row * HID);
        float4* xsv = (float4*)&xs[0][0];
        int rows_valid = N_NODES - block_row;
        if (rows_valid > 64) rows_valid = 64;
        int max4 = rows_valid * 32;
        for (int i = tid; i < 64 * 32; i += 256) {
            xsv[i] = (i < max4) ? Xv[i] : make_float4(0.f, 0.f, 0.f, 0.f);
        }
    }
    __syncthreads();

    const int cg = (tid & 31) * 4;   // column base
    const int r0 = (tid >> 5) * 8;   // row base

    float acc[8][4];
#pragma unroll
    for (int r = 0; r < 8; ++r)
#pragma unroll
        for (int j = 0; j < 4; ++j) acc[r][j] = 0.f;

#pragma unroll 4
    for (int k = 0; k < HID; ++k) {
        const float4 w4 = *(const float4*)(W + k * HID + cg);
#pragma unroll
        for (int r = 0; r < 8; ++r) {
            const float xv = xs[r0 + r][k];
            acc[r][0] = fmaf(xv, w4.x, acc[r][0]);
            acc[r][1] = fmaf(xv, w4.y, acc[r][1]);
            acc[r][2] = fmaf(xv, w4.z, acc[r][2]);
            acc[r][3] = fmaf(xv, w4.w, acc[r][3]);
        }
    }

    const float4 bv = *(const float4*)(bias + cg);
#pragma unroll
    for (int r = 0; r < 8; ++r) {
        const int row = block_row + r0 + r;
        if (row < N_NODES) {
            const float dv = dinv[row];
            const float sn = dv * dv;      // self-loop norm 1/deg
            float4 hv = make_float4(acc[r][0], acc[r][1], acc[r][2], acc[r][3]);
            *(float4*)(hout + (size_t)row * HID + cg) = hv;
            float4 av = make_float4(fmaf(hv.x, sn, bv.x), fmaf(hv.y, sn, bv.y),
                                    fmaf(hv.z, sn, bv.z), fmaf(hv.w, sn, bv.w));
            *(float4*)(aggout + (size_t)row * HID + cg) = av;
        }
    }
}

// ---------------- edge aggregation: agg[dst] += h[src] * dinv[src]*dinv[dst] ----------------
// one wave per edge, float2 per lane
__global__ __launch_bounds__(256) void edge_agg_kernel(const int* __restrict__ ei,
                                                       const float* __restrict__ dinv,
                                                       const float* __restrict__ h,
                                                       float* __restrict__ agg) {
    const int lane = threadIdx.x & 63;
    int wid = (blockIdx.x * 256 + threadIdx.x) >> 6;
    const int nw = (gridDim.x * 256) >> 6;
    for (int e = wid; e < N_EDGES; e += nw) {
        const int src = ei[e];
        const int dst = ei[N_EDGES + e];
        const float nrm = dinv[src] * dinv[dst];
        const int c = lane * 2;
        const float2 v = *(const float2*)(h + (size_t)src * HID + c);
        float* p = agg + (size_t)dst * HID + c;
        atomicAdd(p, v.x * nrm);
        atomicAdd(p + 1, v.y * nrm);
    }
}

// ---------------- batch-norm stats: per-column sum / sumsq ----------------
__global__ __launch_bounds__(256) void bn_stats_kernel(const float* __restrict__ a,
                                                       float* __restrict__ stats) {
    const int c = threadIdx.x & 127;
    const int half = threadIdx.x >> 7;    // 0/1
    const int row0 = blockIdx.x * 128;
    int rend = row0 + 128;
    if (rend > N_NODES) rend = N_NODES;
    float s = 0.f, sq = 0.f;
    for (int r = row0 + half; r < rend; r += 2) {
        const float v = a[(size_t)r * HID + c];
        s += v;
        sq = fmaf(v, v, sq);
    }
    __shared__ float sh[2][2][128];
    sh[0][half][c] = s;
    sh[1][half][c] = sq;
    __syncthreads();
    if (half == 0) {
        atomicAdd(&stats[c], sh[0][0][c] + sh[0][1][c]);
        atomicAdd(&stats[HID + c], sh[1][0][c] + sh[1][1][c]);
    }
}

// stats -> scale/shift (in place)
__global__ __launch_bounds__(128) void bn_fin_kernel(float* __restrict__ stats,
                                                     const float* __restrict__ gamma,
                                                     const float* __restrict__ beta) {
    const int c = threadIdx.x;
    const float invN = 1.0f / (float)N_NODES;
    const float mu = stats[c] * invN;
    const float var = stats[HID + c] * invN - mu * mu;
    const float scale = rsqrtf(var + BN_EPS) * gamma[c];
    stats[c] = scale;
    stats[HID + c] = fmaf(-mu, scale, beta[c]);
}

// apply BN + ReLU
__global__ __launch_bounds__(256) void bn_apply_kernel(const float* __restrict__ a,
                                                       const float* __restrict__ stats,
                                                       float* __restrict__ out) {
    int i = blockIdx.x * 256 + threadIdx.x;
    const int stride = gridDim.x * 256;
    const int total4 = N_NODES * 32;
    for (; i < total4; i += stride) {
        const int c4 = (i & 31) * 4;
        const float4 v = *(const float4*)(a + (size_t)i * 4);
        const float4 sc = *(const float4*)(stats + c4);
        const float4 sh = *(const float4*)(stats + HID + c4);
        float4 o;
        o.x = fmaxf(fmaf(v.x, sc.x, sh.x), 0.f);
        o.y = fmaxf(fmaf(v.y, sc.y, sh.y), 0.f);
        o.z = fmaxf(fmaf(v.z, sc.z, sh.z), 0.f);
        o.w = fmaxf(fmaf(v.w, sc.w, sh.w), 0.f);
        *(float4*)(out + (size_t)i * 4) = o;
    }
}

// ---------------- pooling: per-graph mean-sum + max (ReLU fused) ----------------
__global__ __launch_bounds__(256) void pool_kernel(const float* __restrict__ a,
                                                   const int* __restrict__ batch,
                                                   float* __restrict__ z,
                                                   float* __restrict__ cnt) {
    int idx = blockIdx.x * 256 + threadIdx.x;
    const int stride = gridDim.x * 256;
    const int total = N_NODES * HID;
    for (; idx < total; idx += stride) {
        const int i = idx >> 7;
        const int c = idx & 127;
        const int g = batch[i];
        const float v = fmaxf(a[idx], 0.f);   // layer-4 ReLU fused here
        atomicAdd(&z[g * 256 + c], v);
        atomicMax((int*)&z[g * 256 + 128 + c], __float_as_int(v));  // v >= 0
        if (c == 0) atomicAdd(&cnt[g], 1.0f);
    }
}

// ---------------- head: z=[mean|max] -> relu(z@lw1+lb1) @ lw2 + lb2 ----------------
__global__ __launch_bounds__(128) void head_kernel(const float* __restrict__ z,
                                                   const float* __restrict__ cnt,
                                                   const float* __restrict__ lw1,
                                                   const float* __restrict__ lb1,
                                                   const float* __restrict__ lw2,
                                                   const float* __restrict__ lb2,
                                                   float* __restrict__ out) {
    __shared__ float zin[256];
    __shared__ float z1[128];
    const int g = blockIdx.x;
    const int t = threadIdx.x;
    const float invc = 1.0f / cnt[g];
    zin[t] = z[g * 256 + t] * invc;        // mean
    zin[128 + t] = z[g * 256 + 128 + t];   // max
    __syncthreads();
    float accv = lb1[t];
#pragma unroll 4
    for (int k = 0; k < 256; ++k) accv = fmaf(zin[k], lw1[k * 128 + t], accv);
    z1[t] = fmaxf(accv, 0.f);
    __syncthreads();
    if (t < 10) {
        float o = lb2[t];
#pragma unroll 4
        for (int k = 0; k < 128; ++k) o = fmaf(z1[k], lw2[k * 10 + t], o);
        out[g * 10 + t] = o;
    }
}

// ---------------- launch ----------------
extern "C" void kernel_launch(void* const* d_in, const int* in_sizes, int n_in,
                              void* d_out, int out_size, void* d_ws, size_t ws_size,
                              hipStream_t stream) {
    const float* x     = (const float*)d_in[0];
    const int*   ei    = (const int*)d_in[1];
    const int*   batch = (const int*)d_in[2];
    const float* W[4]  = {(const float*)d_in[3], (const float*)d_in[5],
                          (const float*)d_in[7], (const float*)d_in[9]};
    const float* B[4]  = {(const float*)d_in[4], (const float*)d_in[6],
                          (const float*)d_in[8], (const float*)d_in[10]};
    const float* Gm[3] = {(const float*)d_in[11], (const float*)d_in[13],
                          (const float*)d_in[15]};
    const float* Be[3] = {(const float*)d_in[12], (const float*)d_in[14],
                          (const float*)d_in[16]};
    const float* lw1 = (const float*)d_in[17];
    const float* lb1 = (const float*)d_in[18];
    const float* lw2 = (const float*)d_in[19];
    const float* lb2 = (const float*)d_in[20];

    float* ws = (float*)d_ws;
    float* dinv   = ws;                      // N
    float* stats  = ws + 50000;              // 256
    float* cnt    = ws + 50256;              // 64
    float* z      = ws + 50320;              // G*256 = 16384
    float* hbuf   = ws + 66704;              // N*128
    float* outbuf = ws + 6466704;            // N*128
    float* xbuf   = ws + 12866704;           // N*128

    // degree / dinv
    hipMemsetAsync(dinv, 0, N_NODES * sizeof(float), stream);
    deg_count_kernel<<<2048, 256, 0, stream>>>(ei, dinv);
    deg_fin_kernel<<<(N_NODES + 255) / 256, 256, 0, stream>>>(dinv);

    const float* cur = x;
    for (int l = 0; l < 4; ++l) {
        gemm_kernel<<<(N_NODES + 63) / 64, 256, 0, stream>>>(cur, W[l], B[l], dinv,
                                                             hbuf, outbuf);
        edge_agg_kernel<<<12800, 256, 0, stream>>>(ei, dinv, hbuf, outbuf);
        if (l < 3) {
            hipMemsetAsync(stats, 0, 256 * sizeof(float), stream);
            bn_stats_kernel<<<(N_NODES + 127) / 128, 256, 0, stream>>>(outbuf, stats);
            bn_fin_kernel<<<1, 128, 0, stream>>>(stats, Gm[l], Be[l]);
            bn_apply_kernel<<<6250, 256, 0, stream>>>(outbuf, stats, xbuf);
            cur = xbuf;
        }
    }

    // pooling + head
    hipMemsetAsync(cnt, 0, (64 + 16384) * sizeof(float), stream);  // cnt + z contiguous
    pool_kernel<<<8192, 256, 0, stream>>>(outbuf, batch, z, cnt);
    head_kernel<<<NGRAPH, 128, 0, stream>>>(z, cnt, lw1, lb1, lw2, lb2, (float*)d_out);
}

// Round 3
// 920.916 us; speedup vs baseline: 3.5730x; 3.5730x over previous
//
#include <hip/hip_runtime.h>

#define N_NODES 50000
#define N_EDGES 800000
#define HID     128
#define NGRAPH  64
#define BN_EPS  1e-5f

// ---------------- CSR build ----------------
__global__ __launch_bounds__(256) void deg_counti_kernel(const int* __restrict__ ei,
                                                         int* __restrict__ degi) {
    int i = blockIdx.x * 256 + threadIdx.x;
    if (i < N_EDGES) atomicAdd(&degi[ei[N_EDGES + i]], 1);
}

__global__ __launch_bounds__(256) void deg_fin_kernel(const int* __restrict__ degi,
                                                      float* __restrict__ dinv) {
    int i = blockIdx.x * 256 + threadIdx.x;
    if (i < N_NODES) dinv[i] = rsqrtf((float)degi[i] + 1.0f);   // +1 self loop
}

// exclusive scan of degi -> row_start[0..N], single block
__global__ __launch_bounds__(512) void scan_kernel(const int* __restrict__ degi,
                                                   int* __restrict__ row_start) {
    __shared__ int part[512];
    const int t = threadIdx.x;
    const int per = (N_NODES + 511) / 512;   // 98
    const int b0 = t * per;
    int s = 0;
    for (int i = b0; i < b0 + per && i < N_NODES; ++i) s += degi[i];
    part[t] = s;
    __syncthreads();
    if (t == 0) {
        int run = 0;
        for (int i = 0; i < 512; ++i) { int v = part[i]; part[i] = run; run += v; }
    }
    __syncthreads();
    int run = part[t];
    for (int i = b0; i < b0 + per && i < N_NODES; ++i) { row_start[i] = run; run += degi[i]; }
    if (t == 511) row_start[N_NODES] = run;   // == E
}

__global__ __launch_bounds__(256) void scatter_kernel(const int* __restrict__ ei,
                                                      const float* __restrict__ dinv,
                                                      const int* __restrict__ row_start,
                                                      int* __restrict__ cursor,
                                                      int* __restrict__ csr_src,
                                                      float* __restrict__ csr_w) {
    int e = blockIdx.x * 256 + threadIdx.x;
    if (e >= N_EDGES) return;
    const int src = ei[e];
    const int dst = ei[N_EDGES + e];
    const int pos = row_start[dst] + atomicAdd(&cursor[dst], 1);
    csr_src[pos] = src;
    csr_w[pos] = dinv[src] * dinv[dst];
}

// graph boundaries from sorted batch vector
__global__ __launch_bounds__(256) void bounds_kernel(const int* __restrict__ batch,
                                                     int* __restrict__ bound) {
    int i = blockIdx.x * 256 + threadIdx.x;
    if (i >= N_NODES) return;
    const int b = batch[i];
    if (i == 0) {
        for (int g = 0; g <= b; ++g) bound[g] = 0;
    } else {
        const int pb = batch[i - 1];
        for (int g = pb + 1; g <= b; ++g) bound[g] = i;
    }
    if (i == N_NODES - 1) {
        for (int g = b + 1; g <= NGRAPH; ++g) bound[g] = N_NODES;
    }
}

// ---------------- GEMM: h = X @ W ; agg_init = h*dinv^2 + b ----------------
// In-place safe for X==aggout: each block stages its 64 rows to LDS before writing.
__global__ __launch_bounds__(256) void gemm_kernel(const float* __restrict__ X,
                                                   const float* __restrict__ W,
                                                   const float* __restrict__ bias,
                                                   const float* __restrict__ dinv,
                                                   float* __restrict__ hout,
                                                   float* __restrict__ aggout) {
    __shared__ float xs[64][128];
    const int tid = threadIdx.x;
    const int block_row = blockIdx.x * 64;

    {
        const float4* Xv = (const float4*)(X + (size_t)block_row * HID);
        float4* xsv = (float4*)&xs[0][0];
        int rows_valid = N_NODES - block_row;
        if (rows_valid > 64) rows_valid = 64;
        const int max4 = rows_valid * 32;
        for (int i = tid; i < 64 * 32; i += 256)
            xsv[i] = (i < max4) ? Xv[i] : make_float4(0.f, 0.f, 0.f, 0.f);
    }
    __syncthreads();

    const int cg = (tid & 31) * 4;
    const int r0 = (tid >> 5) * 8;

    float acc[8][4];
#pragma unroll
    for (int r = 0; r < 8; ++r)
#pragma unroll
        for (int j = 0; j < 4; ++j) acc[r][j] = 0.f;

#pragma unroll 4
    for (int k = 0; k < HID; ++k) {
        const float4 w4 = *(const float4*)(W + k * HID + cg);
#pragma unroll
        for (int r = 0; r < 8; ++r) {
            const float xv = xs[r0 + r][k];
            acc[r][0] = fmaf(xv, w4.x, acc[r][0]);
            acc[r][1] = fmaf(xv, w4.y, acc[r][1]);
            acc[r][2] = fmaf(xv, w4.z, acc[r][2]);
            acc[r][3] = fmaf(xv, w4.w, acc[r][3]);
        }
    }

    const float4 bv = *(const float4*)(bias + cg);
#pragma unroll
    for (int r = 0; r < 8; ++r) {
        const int row = block_row + r0 + r;
        if (row < N_NODES) {
            const float dv = dinv[row];
            const float sn = dv * dv;
            float4 hv = make_float4(acc[r][0], acc[r][1], acc[r][2], acc[r][3]);
            *(float4*)(hout + (size_t)row * HID + cg) = hv;
            float4 av = make_float4(fmaf(hv.x, sn, bv.x), fmaf(hv.y, sn, bv.y),
                                    fmaf(hv.z, sn, bv.z), fmaf(hv.w, sn, bv.w));
            *(float4*)(aggout + (size_t)row * HID + cg) = av;
        }
    }
}

// ---------------- aggregation: gather over CSR, one wave per dst node ----------------
__global__ __launch_bounds__(256) void agg_csr_kernel(const int* __restrict__ row_start,
                                                      const int* __restrict__ csr_src,
                                                      const float* __restrict__ csr_w,
                                                      const float* __restrict__ h,
                                                      float* __restrict__ agg) {
    const int node = blockIdx.x * 4 + (threadIdx.x >> 6);
    if (node >= N_NODES) return;
    const int lane = threadIdx.x & 63;
    const int c = lane * 2;
    const int beg = row_start[node];
    const int end = row_start[node + 1];
    float* ap = agg + (size_t)node * HID + c;
    float2 acc = *(const float2*)ap;   // self term + bias (from gemm epilogue)
    for (int p = beg; p < end; ++p) {
        const int src = csr_src[p];
        const float w = csr_w[p];
        const float2 v = *(const float2*)(h + (size_t)src * HID + c);
        acc.x = fmaf(v.x, w, acc.x);
        acc.y = fmaf(v.y, w, acc.y);
    }
    *(float2*)ap = acc;
}

// ---------------- batch-norm ----------------
__global__ __launch_bounds__(256) void bn_stats_kernel(const float* __restrict__ a,
                                                       float* __restrict__ stats) {
    const int c = threadIdx.x & 127;
    const int half = threadIdx.x >> 7;
    const int row0 = blockIdx.x * 128;
    int rend = row0 + 128;
    if (rend > N_NODES) rend = N_NODES;
    float s = 0.f, sq = 0.f;
    for (int r = row0 + half; r < rend; r += 2) {
        const float v = a[(size_t)r * HID + c];
        s += v;
        sq = fmaf(v, v, sq);
    }
    __shared__ float sh[2][2][128];
    sh[0][half][c] = s;
    sh[1][half][c] = sq;
    __syncthreads();
    if (half == 0) {
        atomicAdd(&stats[c], sh[0][0][c] + sh[0][1][c]);
        atomicAdd(&stats[HID + c], sh[1][0][c] + sh[1][1][c]);
    }
}

__global__ __launch_bounds__(128) void bn_fin_kernel(float* __restrict__ stats,
                                                     const float* __restrict__ gamma,
                                                     const float* __restrict__ beta) {
    const int c = threadIdx.x;
    const float invN = 1.0f / (float)N_NODES;
    const float mu = stats[c] * invN;
    const float var = stats[HID + c] * invN - mu * mu;
    const float scale = rsqrtf(var + BN_EPS) * gamma[c];
    stats[c] = scale;
    stats[HID + c] = fmaf(-mu, scale, beta[c]);
}

// BN + ReLU, in place
__global__ __launch_bounds__(256) void bn_apply_kernel(float* __restrict__ a,
                                                       const float* __restrict__ stats) {
    int i = blockIdx.x * 256 + threadIdx.x;
    const int stride = gridDim.x * 256;
    const int total4 = N_NODES * 32;
    for (; i < total4; i += stride) {
        const int c4 = (i & 31) * 4;
        const float4 v = *(const float4*)(a + (size_t)i * 4);
        const float4 sc = *(const float4*)(stats + c4);
        const float4 sh = *(const float4*)(stats + HID + c4);
        float4 o;
        o.x = fmaxf(fmaf(v.x, sc.x, sh.x), 0.f);
        o.y = fmaxf(fmaf(v.y, sc.y, sh.y), 0.f);
        o.z = fmaxf(fmaf(v.z, sc.z, sh.z), 0.f);
        o.w = fmaxf(fmaf(v.w, sc.w, sh.w), 0.f);
        *(float4*)(a + (size_t)i * 4) = o;
    }
}

// ---------------- pooling: segmented (batch is sorted), no atomics ----------------
// grid (NGRAPH, 4): 32 cols per block, 8 row-parities
__global__ __launch_bounds__(256) void pool_seg_kernel(const float* __restrict__ a,
                                                       const int* __restrict__ bound,
                                                       float* __restrict__ z) {
    const int g = blockIdx.x;
    const int cl = threadIdx.x & 31;
    const int c = blockIdx.y * 32 + cl;
    const int par = threadIdx.x >> 5;      // 0..7
    const int beg = bound[g], end = bound[g + 1];
    float s = 0.f, m = 0.f;                // post-ReLU values >= 0
    for (int r = beg + par; r < end; r += 8) {
        const float v = fmaxf(a[(size_t)r * HID + c], 0.f);   // layer-4 ReLU fused
        s += v;
        m = fmaxf(m, v);
    }
    __shared__ float ssum[8][32];
    __shared__ float smax[8][32];
    ssum[par][cl] = s;
    smax[par][cl] = m;
    __syncthreads();
    if (par == 0) {
        float ts = 0.f, tm = 0.f;
#pragma unroll
        for (int p = 0; p < 8; ++p) { ts += ssum[p][cl]; tm = fmaxf(tm, smax[p][cl]); }
        const float cntf = (float)(end - beg);
        z[g * 256 + c] = ts / fmaxf(cntf, 1.f);   // mean
        z[g * 256 + 128 + c] = tm;                // max
    }
}

// ---------------- head ----------------
__global__ __launch_bounds__(128) void head_kernel(const float* __restrict__ z,
                                                   const float* __restrict__ lw1,
                                                   const float* __restrict__ lb1,
                                                   const float* __restrict__ lw2,
                                                   const float* __restrict__ lb2,
                                                   float* __restrict__ out) {
    __shared__ float zin[256];
    __shared__ float z1[128];
    const int g = blockIdx.x;
    const int t = threadIdx.x;
    zin[t] = z[g * 256 + t];
    zin[128 + t] = z[g * 256 + 128 + t];
    __syncthreads();
    float accv = lb1[t];
#pragma unroll 4
    for (int k = 0; k < 256; ++k) accv = fmaf(zin[k], lw1[k * 128 + t], accv);
    z1[t] = fmaxf(accv, 0.f);
    __syncthreads();
    if (t < 10) {
        float o = lb2[t];
#pragma unroll 4
        for (int k = 0; k < 128; ++k) o = fmaf(z1[k], lw2[k * 10 + t], o);
        out[g * 10 + t] = o;
    }
}

// ---------------- launch ----------------
extern "C" void kernel_launch(void* const* d_in, const int* in_sizes, int n_in,
                              void* d_out, int out_size, void* d_ws, size_t ws_size,
                              hipStream_t stream) {
    const float* x     = (const float*)d_in[0];
    const int*   ei    = (const int*)d_in[1];
    const int*   batch = (const int*)d_in[2];
    const float* W[4]  = {(const float*)d_in[3], (const float*)d_in[5],
                          (const float*)d_in[7], (const float*)d_in[9]};
    const float* B[4]  = {(const float*)d_in[4], (const float*)d_in[6],
                          (const float*)d_in[8], (const float*)d_in[10]};
    const float* Gm[3] = {(const float*)d_in[11], (const float*)d_in[13],
                          (const float*)d_in[15]};
    const float* Be[3] = {(const float*)d_in[12], (const float*)d_in[14],
                          (const float*)d_in[16]};
    const float* lw1 = (const float*)d_in[17];
    const float* lb1 = (const float*)d_in[18];
    const float* lw2 = (const float*)d_in[19];
    const float* lb2 = (const float*)d_in[20];

    char* ws = (char*)d_ws;
    float* dinv      = (float*)ws;                          // @0        len 50000
    float* stats     = (float*)(ws + 50000u * 4);           // @50000    len 256
    float* z         = (float*)(ws + 50256u * 4);           // @50256    len 16384
    int*   degi      = (int*)  (ws + 66640u * 4);           // @66640    len 50000
    int*   cursor    = (int*)  (ws + 116640u * 4);          // @116640   len 50000
    int*   row_start = (int*)  (ws + 166640u * 4);          // @166640   len 50001
    int*   bound     = (int*)  (ws + 216644u * 4);          // @216644   len 65
    int*   csr_src   = (int*)  (ws + 216712u * 4);          // @216712   len 800000
    float* csr_w     = (float*)(ws + 1016712u * 4);         // @1016712  len 800000
    float* hbuf      = (float*)(ws + 1816712u * 4);         // @1816712  len 6.4M
    float* abuf      = (float*)(ws + 8216712u * 4);         // @8216712  len 6.4M

    // ---- CSR build (once per launch) ----
    hipMemsetAsync(degi, 0, 100000u * sizeof(int), stream);   // degi + cursor contiguous
    deg_counti_kernel<<<(N_EDGES + 255) / 256, 256, 0, stream>>>(ei, degi);
    deg_fin_kernel<<<(N_NODES + 255) / 256, 256, 0, stream>>>(degi, dinv);
    scan_kernel<<<1, 512, 0, stream>>>(degi, row_start);
    scatter_kernel<<<(N_EDGES + 255) / 256, 256, 0, stream>>>(ei, dinv, row_start,
                                                              cursor, csr_src, csr_w);
    bounds_kernel<<<(N_NODES + 255) / 256, 256, 0, stream>>>(batch, bound);

    // ---- layers ----
    const float* cur = x;
    for (int l = 0; l < 4; ++l) {
        gemm_kernel<<<(N_NODES + 63) / 64, 256, 0, stream>>>(cur, W[l], B[l], dinv,
                                                             hbuf, abuf);
        agg_csr_kernel<<<(N_NODES + 3) / 4, 256, 0, stream>>>(row_start, csr_src,
                                                              csr_w, hbuf, abuf);
        if (l < 3) {
            hipMemsetAsync(stats, 0, 256 * sizeof(float), stream);
            bn_stats_kernel<<<(N_NODES + 127) / 128, 256, 0, stream>>>(abuf, stats);
            bn_fin_kernel<<<1, 128, 0, stream>>>(stats, Gm[l], Be[l]);
            bn_apply_kernel<<<6250, 256, 0, stream>>>(abuf, stats);
        }
        cur = abuf;
    }

    // ---- pooling + head ----
    pool_seg_kernel<<<dim3(NGRAPH, 4), 256, 0, stream>>>(abuf, bound, z);
    head_kernel<<<NGRAPH, 128, 0, stream>>>(z, lw1, lb1, lw2, lb2, (float*)d_out);
}

// Round 4
// 827.812 us; speedup vs baseline: 3.9749x; 1.1125x over previous
//
#include <hip/hip_runtime.h>

#define N_NODES 50000
#define N_EDGES 800000
#define HID     128
#define NGRAPH  64
#define BN_EPS  1e-5f

// ---------------- CSR build ----------------
__global__ __launch_bounds__(256) void deg_counti_kernel(const int* __restrict__ ei,
                                                         int* __restrict__ degi) {
    int i = blockIdx.x * 256 + threadIdx.x;
    if (i < N_EDGES) atomicAdd(&degi[ei[N_EDGES + i]], 1);
}

__global__ __launch_bounds__(256) void deg_fin_kernel(const int* __restrict__ degi,
                                                      float* __restrict__ dinv) {
    int i = blockIdx.x * 256 + threadIdx.x;
    if (i < N_NODES) dinv[i] = rsqrtf((float)degi[i] + 1.0f);   // +1 self loop
}

// exclusive scan of degi -> row_start[0..N], single block
__global__ __launch_bounds__(512) void scan_kernel(const int* __restrict__ degi,
                                                   int* __restrict__ row_start) {
    __shared__ int part[512];
    const int t = threadIdx.x;
    const int per = (N_NODES + 511) / 512;   // 98
    const int b0 = t * per;
    int s = 0;
    for (int i = b0; i < b0 + per && i < N_NODES; ++i) s += degi[i];
    part[t] = s;
    __syncthreads();
    if (t == 0) {
        int run = 0;
        for (int i = 0; i < 512; ++i) { int v = part[i]; part[i] = run; run += v; }
    }
    __syncthreads();
    int run = part[t];
    for (int i = b0; i < b0 + per && i < N_NODES; ++i) { row_start[i] = run; run += degi[i]; }
    if (t == 511) row_start[N_NODES] = run;
}

// pack (src, weight) into one 8B record
__global__ __launch_bounds__(256) void scatter_kernel(const int* __restrict__ ei,
                                                      const float* __restrict__ dinv,
                                                      const int* __restrict__ row_start,
                                                      int* __restrict__ cursor,
                                                      float2* __restrict__ csr_sw) {
    int e = blockIdx.x * 256 + threadIdx.x;
    if (e >= N_EDGES) return;
    const int src = ei[e];
    const int dst = ei[N_EDGES + e];
    const int pos = row_start[dst] + atomicAdd(&cursor[dst], 1);
    float2 sw;
    sw.x = __int_as_float(src);
    sw.y = dinv[src] * dinv[dst];
    csr_sw[pos] = sw;
}

// graph boundaries from sorted batch vector
__global__ __launch_bounds__(256) void bounds_kernel(const int* __restrict__ batch,
                                                     int* __restrict__ bound) {
    int i = blockIdx.x * 256 + threadIdx.x;
    if (i >= N_NODES) return;
    const int b = batch[i];
    if (i == 0) {
        for (int g = 0; g <= b; ++g) bound[g] = 0;
    } else {
        const int pb = batch[i - 1];
        for (int g = pb + 1; g <= b; ++g) bound[g] = i;
    }
    if (i == N_NODES - 1) {
        for (int g = b + 1; g <= NGRAPH; ++g) bound[g] = N_NODES;
    }
}

// ---------------- GEMM: h = bnrelu(X) @ W, W staged in LDS chunks ----------------
__global__ __launch_bounds__(256) void gemm_kernel(const float* __restrict__ X,
                                                   const float* __restrict__ W,
                                                   const float* __restrict__ stats,
                                                   const int use_bn,
                                                   float* __restrict__ hout) {
    __shared__ float xs[64][128];
    __shared__ float wsm[32][128];
    const int tid = threadIdx.x;
    const int block_row = blockIdx.x * 64;

    // stage X tile, fusing BN(scale,shift)+ReLU of the PREVIOUS layer
    {
        const float4* Xv = (const float4*)(X + (size_t)block_row * HID);
        float4* xsv = (float4*)&xs[0][0];
        int rows_valid = N_NODES - block_row;
        if (rows_valid > 64) rows_valid = 64;
        const int max4 = rows_valid * 32;
        for (int i = tid; i < 64 * 32; i += 256) {
            float4 v = (i < max4) ? Xv[i] : make_float4(0.f, 0.f, 0.f, 0.f);
            if (use_bn) {
                const int c4 = (i & 31) * 4;
                const float4 sc = *(const float4*)(stats + c4);
                const float4 sh = *(const float4*)(stats + HID + c4);
                v.x = fmaxf(fmaf(v.x, sc.x, sh.x), 0.f);
                v.y = fmaxf(fmaf(v.y, sc.y, sh.y), 0.f);
                v.z = fmaxf(fmaf(v.z, sc.z, sh.z), 0.f);
                v.w = fmaxf(fmaf(v.w, sc.w, sh.w), 0.f);
            }
            xsv[i] = v;
        }
    }

    const int cg = (tid & 31) * 4;
    const int r0 = (tid >> 5) * 8;

    float acc[8][4];
#pragma unroll
    for (int r = 0; r < 8; ++r)
#pragma unroll
        for (int j = 0; j < 4; ++j) acc[r][j] = 0.f;

    for (int kc = 0; kc < 4; ++kc) {
        __syncthreads();   // xs staged (kc=0) / previous chunk consumed
        {
            const float4* Wv = (const float4*)(W + kc * 32 * HID);
            float4* wsv = (float4*)&wsm[0][0];
            for (int i = tid; i < 32 * 32; i += 256) wsv[i] = Wv[i];
        }
        __syncthreads();
#pragma unroll
        for (int kk = 0; kk < 32; ++kk) {
            const float4 w4 = *(const float4*)(&wsm[kk][cg]);
            const int k = kc * 32 + kk;
#pragma unroll
            for (int r = 0; r < 8; ++r) {
                const float xv = xs[r0 + r][k];
                acc[r][0] = fmaf(xv, w4.x, acc[r][0]);
                acc[r][1] = fmaf(xv, w4.y, acc[r][1]);
                acc[r][2] = fmaf(xv, w4.z, acc[r][2]);
                acc[r][3] = fmaf(xv, w4.w, acc[r][3]);
            }
        }
    }

#pragma unroll
    for (int r = 0; r < 8; ++r) {
        const int row = block_row + r0 + r;
        if (row < N_NODES)
            *(float4*)(hout + (size_t)row * HID + cg) =
                make_float4(acc[r][0], acc[r][1], acc[r][2], acc[r][3]);
    }
}

// ---------------- aggregation: gather over CSR, one wave per dst node ----------------
// agg[node] = h[node]*dinv^2 + bias + sum_e h[src_e]*w_e     (unroll 4, 4 gathers in flight)
__global__ __launch_bounds__(256) void agg_csr_kernel(const int* __restrict__ row_start,
                                                      const float2* __restrict__ csr_sw,
                                                      const float* __restrict__ h,
                                                      const float* __restrict__ dinv,
                                                      const float* __restrict__ bias,
                                                      float* __restrict__ agg) {
    const int node = blockIdx.x * 4 + (threadIdx.x >> 6);
    if (node >= N_NODES) return;
    const int lane = threadIdx.x & 63;
    const int c = lane * 2;
    const int beg = row_start[node];
    const int end = row_start[node + 1];

    const float dv = dinv[node];
    const float sn = dv * dv;
    const float2 hv = *(const float2*)(h + (size_t)node * HID + c);
    const float2 bv = *(const float2*)(bias + c);
    float2 a0 = make_float2(fmaf(hv.x, sn, bv.x), fmaf(hv.y, sn, bv.y));
    float2 a1 = make_float2(0.f, 0.f);
    float2 a2 = make_float2(0.f, 0.f);
    float2 a3 = make_float2(0.f, 0.f);

    int p = beg;
    for (; p + 4 <= end; p += 4) {
        const float2 e0 = csr_sw[p];
        const float2 e1 = csr_sw[p + 1];
        const float2 e2 = csr_sw[p + 2];
        const float2 e3 = csr_sw[p + 3];
        const float2 v0 = *(const float2*)(h + (size_t)__float_as_int(e0.x) * HID + c);
        const float2 v1 = *(const float2*)(h + (size_t)__float_as_int(e1.x) * HID + c);
        const float2 v2 = *(const float2*)(h + (size_t)__float_as_int(e2.x) * HID + c);
        const float2 v3 = *(const float2*)(h + (size_t)__float_as_int(e3.x) * HID + c);
        a0.x = fmaf(v0.x, e0.y, a0.x); a0.y = fmaf(v0.y, e0.y, a0.y);
        a1.x = fmaf(v1.x, e1.y, a1.x); a1.y = fmaf(v1.y, e1.y, a1.y);
        a2.x = fmaf(v2.x, e2.y, a2.x); a2.y = fmaf(v2.y, e2.y, a2.y);
        a3.x = fmaf(v3.x, e3.y, a3.x); a3.y = fmaf(v3.y, e3.y, a3.y);
    }
    for (; p < end; ++p) {
        const float2 e0 = csr_sw[p];
        const float2 v0 = *(const float2*)(h + (size_t)__float_as_int(e0.x) * HID + c);
        a0.x = fmaf(v0.x, e0.y, a0.x); a0.y = fmaf(v0.y, e0.y, a0.y);
    }
    a0.x += (a1.x + a2.x) + a3.x;
    a0.y += (a1.y + a2.y) + a3.y;
    *(float2*)(agg + (size_t)node * HID + c) = a0;
}

// ---------------- batch-norm stats ----------------
__global__ __launch_bounds__(256) void bn_stats_kernel(const float* __restrict__ a,
                                                       float* __restrict__ stats) {
    const int c = threadIdx.x & 127;
    const int half = threadIdx.x >> 7;
    const int row0 = blockIdx.x * 128;
    int rend = row0 + 128;
    if (rend > N_NODES) rend = N_NODES;
    float s = 0.f, sq = 0.f;
    for (int r = row0 + half; r < rend; r += 2) {
        const float v = a[(size_t)r * HID + c];
        s += v;
        sq = fmaf(v, v, sq);
    }
    __shared__ float sh[2][2][128];
    sh[0][half][c] = s;
    sh[1][half][c] = sq;
    __syncthreads();
    if (half == 0) {
        atomicAdd(&stats[c], sh[0][0][c] + sh[0][1][c]);
        atomicAdd(&stats[HID + c], sh[1][0][c] + sh[1][1][c]);
    }
}

__global__ __launch_bounds__(128) void bn_fin_kernel(float* __restrict__ stats,
                                                     const float* __restrict__ gamma,
                                                     const float* __restrict__ beta) {
    const int c = threadIdx.x;
    const float invN = 1.0f / (float)N_NODES;
    const float mu = stats[c] * invN;
    const float var = stats[HID + c] * invN - mu * mu;
    const float scale = rsqrtf(var + BN_EPS) * gamma[c];
    stats[c] = scale;
    stats[HID + c] = fmaf(-mu, scale, beta[c]);
}

// ---------------- pooling: segmented (batch is sorted) ----------------
__global__ __launch_bounds__(256) void pool_seg_kernel(const float* __restrict__ a,
                                                       const int* __restrict__ bound,
                                                       float* __restrict__ z) {
    const int g = blockIdx.x;
    const int cl = threadIdx.x & 31;
    const int c = blockIdx.y * 32 + cl;
    const int par = threadIdx.x >> 5;
    const int beg = bound[g], end = bound[g + 1];
    float s = 0.f, m = 0.f;
    for (int r = beg + par; r < end; r += 8) {
        const float v = fmaxf(a[(size_t)r * HID + c], 0.f);   // layer-4 ReLU fused
        s += v;
        m = fmaxf(m, v);
    }
    __shared__ float ssum[8][32];
    __shared__ float smax[8][32];
    ssum[par][cl] = s;
    smax[par][cl] = m;
    __syncthreads();
    if (par == 0) {
        float ts = 0.f, tm = 0.f;
#pragma unroll
        for (int p = 0; p < 8; ++p) { ts += ssum[p][cl]; tm = fmaxf(tm, smax[p][cl]); }
        const float cntf = (float)(end - beg);
        z[g * 256 + c] = ts / fmaxf(cntf, 1.f);
        z[g * 256 + 128 + c] = tm;
    }
}

// ---------------- head ----------------
__global__ __launch_bounds__(128) void head_kernel(const float* __restrict__ z,
                                                   const float* __restrict__ lw1,
                                                   const float* __restrict__ lb1,
                                                   const float* __restrict__ lw2,
                                                   const float* __restrict__ lb2,
                                                   float* __restrict__ out) {
    __shared__ float zin[256];
    __shared__ float z1[128];
    const int g = blockIdx.x;
    const int t = threadIdx.x;
    zin[t] = z[g * 256 + t];
    zin[128 + t] = z[g * 256 + 128 + t];
    __syncthreads();
    float accv = lb1[t];
#pragma unroll 4
    for (int k = 0; k < 256; ++k) accv = fmaf(zin[k], lw1[k * 128 + t], accv);
    z1[t] = fmaxf(accv, 0.f);
    __syncthreads();
    if (t < 10) {
        float o = lb2[t];
#pragma unroll 4
        for (int k = 0; k < 128; ++k) o = fmaf(z1[k], lw2[k * 10 + t], o);
        out[g * 10 + t] = o;
    }
}

// ---------------- launch ----------------
extern "C" void kernel_launch(void* const* d_in, const int* in_sizes, int n_in,
                              void* d_out, int out_size, void* d_ws, size_t ws_size,
                              hipStream_t stream) {
    const float* x     = (const float*)d_in[0];
    const int*   ei    = (const int*)d_in[1];
    const int*   batch = (const int*)d_in[2];
    const float* W[4]  = {(const float*)d_in[3], (const float*)d_in[5],
                          (const float*)d_in[7], (const float*)d_in[9]};
    const float* B[4]  = {(const float*)d_in[4], (const float*)d_in[6],
                          (const float*)d_in[8], (const float*)d_in[10]};
    const float* Gm[3] = {(const float*)d_in[11], (const float*)d_in[13],
                          (const float*)d_in[15]};
    const float* Be[3] = {(const float*)d_in[12], (const float*)d_in[14],
                          (const float*)d_in[16]};
    const float* lw1 = (const float*)d_in[17];
    const float* lb1 = (const float*)d_in[18];
    const float* lw2 = (const float*)d_in[19];
    const float* lb2 = (const float*)d_in[20];

    char* ws = (char*)d_ws;
    float*  dinv      = (float*)ws;                          // @0        len 50000
    float*  stats     = (float*)(ws + 50000u * 4);           // @50000    len 256
    float*  z         = (float*)(ws + 50256u * 4);           // @50256    len 16384
    int*    degi      = (int*)  (ws + 66640u * 4);           // @66640    len 50000
    int*    cursor    = (int*)  (ws + 116640u * 4);          // @116640   len 50000
    int*    row_start = (int*)  (ws + 166640u * 4);          // @166640   len 50001
    int*    bound     = (int*)  (ws + 216644u * 4);          // @216644   len 65
    float2* csr_sw    = (float2*)(ws + 216712u * 4);         // @216712   len 2*800000 (8B-aligned)
    float*  hbuf      = (float*)(ws + 1816712u * 4);         // @1816712  len 6.4M
    float*  abuf      = (float*)(ws + 8216712u * 4);         // @8216712  len 6.4M

    // ---- CSR build (once per launch) ----
    hipMemsetAsync(degi, 0, 100000u * sizeof(int), stream);   // degi + cursor contiguous
    deg_counti_kernel<<<(N_EDGES + 255) / 256, 256, 0, stream>>>(ei, degi);
    deg_fin_kernel<<<(N_NODES + 255) / 256, 256, 0, stream>>>(degi, dinv);
    scan_kernel<<<1, 512, 0, stream>>>(degi, row_start);
    scatter_kernel<<<(N_EDGES + 255) / 256, 256, 0, stream>>>(ei, dinv, row_start,
                                                              cursor, csr_sw);
    bounds_kernel<<<(N_NODES + 255) / 256, 256, 0, stream>>>(batch, bound);

    // ---- layers ----
    const float* cur = x;
    for (int l = 0; l < 4; ++l) {
        gemm_kernel<<<(N_NODES + 63) / 64, 256, 0, stream>>>(cur, W[l], stats,
                                                             l > 0 ? 1 : 0, hbuf);
        agg_csr_kernel<<<(N_NODES + 3) / 4, 256, 0, stream>>>(row_start, csr_sw, hbuf,
                                                              dinv, B[l], abuf);
        if (l < 3) {
            hipMemsetAsync(stats, 0, 256 * sizeof(float), stream);
            bn_stats_kernel<<<(N_NODES + 127) / 128, 256, 0, stream>>>(abuf, stats);
            bn_fin_kernel<<<1, 128, 0, stream>>>(stats, Gm[l], Be[l]);
        }
        cur = abuf;
    }

    // ---- pooling + head ----
    pool_seg_kernel<<<dim3(NGRAPH, 4), 256, 0, stream>>>(abuf, bound, z);
    head_kernel<<<NGRAPH, 128, 0, stream>>>(z, lw1, lb1, lw2, lb2, (float*)d_out);
}

// Round 5
// 750.990 us; speedup vs baseline: 4.3815x; 1.1023x over previous
//
#include <hip/hip_runtime.h>

#define N_NODES 50000
#define N_EDGES 800000
#define HID     128
#define NGRAPH  64
#define BN_EPS  1e-5f
#define SCAN_B  98   // ceil(50000/512)

// ---------------- CSR build ----------------
__global__ __launch_bounds__(256) void deg_counti_kernel(const int* __restrict__ ei,
                                                         int* __restrict__ degi) {
    int i = blockIdx.x * 256 + threadIdx.x;
    if (i < N_EDGES) atomicAdd(&degi[ei[N_EDGES + i]], 1);
}

__global__ __launch_bounds__(256) void deg_fin_kernel(const int* __restrict__ degi,
                                                      float* __restrict__ dinv) {
    int i = blockIdx.x * 256 + threadIdx.x;
    if (i < N_NODES) dinv[i] = rsqrtf((float)degi[i] + 1.0f);   // +1 self loop
}

// ---- hierarchical exclusive scan: degi -> row_start[0..N] ----
__global__ __launch_bounds__(512) void scan1_kernel(const int* __restrict__ degi,
                                                    int* __restrict__ row_start,
                                                    int* __restrict__ partials) {
    __shared__ int sh[512];
    const int t = threadIdx.x;
    const int i = blockIdx.x * 512 + t;
    const int v = (i < N_NODES) ? degi[i] : 0;
    sh[t] = v;
    __syncthreads();
#pragma unroll
    for (int off = 1; off < 512; off <<= 1) {
        const int add = (t >= off) ? sh[t - off] : 0;
        __syncthreads();
        sh[t] += add;
        __syncthreads();
    }
    if (i < N_NODES) row_start[i] = sh[t] - v;   // local exclusive prefix
    if (t == 511) partials[blockIdx.x] = sh[511];
}

__global__ __launch_bounds__(128) void scan2_kernel(int* __restrict__ partials,
                                                    int* __restrict__ row_start) {
    __shared__ int sh[SCAN_B + 1];
    const int t = threadIdx.x;
    if (t < SCAN_B) sh[t] = partials[t];
    __syncthreads();
    if (t == 0) {
        int run = 0;
        for (int b = 0; b < SCAN_B; ++b) { const int v = sh[b]; sh[b] = run; run += v; }
        sh[SCAN_B] = run;
    }
    __syncthreads();
    if (t < SCAN_B) partials[t] = sh[t];
    if (t == 0) row_start[N_NODES] = sh[SCAN_B];   // == E
}

__global__ __launch_bounds__(512) void scan3_kernel(int* __restrict__ row_start,
                                                    const int* __restrict__ partials) {
    const int i = blockIdx.x * 512 + threadIdx.x;
    if (i < N_NODES) row_start[i] += partials[blockIdx.x];
}

// pack (src, weight) into one 8B record
__global__ __launch_bounds__(256) void scatter_kernel(const int* __restrict__ ei,
                                                      const float* __restrict__ dinv,
                                                      const int* __restrict__ row_start,
                                                      int* __restrict__ cursor,
                                                      float2* __restrict__ csr_sw) {
    int e = blockIdx.x * 256 + threadIdx.x;
    if (e >= N_EDGES) return;
    const int src = ei[e];
    const int dst = ei[N_EDGES + e];
    const int pos = row_start[dst] + atomicAdd(&cursor[dst], 1);
    float2 sw;
    sw.x = __int_as_float(src);
    sw.y = dinv[src] * dinv[dst];
    csr_sw[pos] = sw;
}

// graph boundaries from sorted batch vector
__global__ __launch_bounds__(256) void bounds_kernel(const int* __restrict__ batch,
                                                     int* __restrict__ bound) {
    int i = blockIdx.x * 256 + threadIdx.x;
    if (i >= N_NODES) return;
    const int b = batch[i];
    if (i == 0) {
        for (int g = 0; g <= b; ++g) bound[g] = 0;
    } else {
        const int pb = batch[i - 1];
        for (int g = pb + 1; g <= b; ++g) bound[g] = i;
    }
    if (i == N_NODES - 1) {
        for (int g = b + 1; g <= NGRAPH; ++g) bound[g] = N_NODES;
    }
}

// ---------------- GEMM: h = bnrelu(X) @ W, W staged in LDS chunks ----------------
__global__ __launch_bounds__(256) void gemm_kernel(const float* __restrict__ X,
                                                   const float* __restrict__ W,
                                                   const float* __restrict__ stats,
                                                   const int use_bn,
                                                   float* __restrict__ hout) {
    __shared__ float xs[64][128];
    __shared__ float wsm[32][128];
    const int tid = threadIdx.x;
    const int block_row = blockIdx.x * 64;

    // stage X tile, fusing BN(scale,shift)+ReLU of the PREVIOUS layer
    {
        const float4* Xv = (const float4*)(X + (size_t)block_row * HID);
        float4* xsv = (float4*)&xs[0][0];
        int rows_valid = N_NODES - block_row;
        if (rows_valid > 64) rows_valid = 64;
        const int max4 = rows_valid * 32;
        for (int i = tid; i < 64 * 32; i += 256) {
            float4 v = (i < max4) ? Xv[i] : make_float4(0.f, 0.f, 0.f, 0.f);
            if (use_bn) {
                const int c4 = (i & 31) * 4;
                const float4 sc = *(const float4*)(stats + c4);
                const float4 sh = *(const float4*)(stats + HID + c4);
                v.x = fmaxf(fmaf(v.x, sc.x, sh.x), 0.f);
                v.y = fmaxf(fmaf(v.y, sc.y, sh.y), 0.f);
                v.z = fmaxf(fmaf(v.z, sc.z, sh.z), 0.f);
                v.w = fmaxf(fmaf(v.w, sc.w, sh.w), 0.f);
            }
            xsv[i] = v;
        }
    }

    const int cg = (tid & 31) * 4;
    const int r0 = (tid >> 5) * 8;

    float acc[8][4];
#pragma unroll
    for (int r = 0; r < 8; ++r)
#pragma unroll
        for (int j = 0; j < 4; ++j) acc[r][j] = 0.f;

    for (int kc = 0; kc < 4; ++kc) {
        __syncthreads();
        {
            const float4* Wv = (const float4*)(W + kc * 32 * HID);
            float4* wsv = (float4*)&wsm[0][0];
            for (int i = tid; i < 32 * 32; i += 256) wsv[i] = Wv[i];
        }
        __syncthreads();
#pragma unroll
        for (int kk = 0; kk < 32; ++kk) {
            const float4 w4 = *(const float4*)(&wsm[kk][cg]);
            const int k = kc * 32 + kk;
#pragma unroll
            for (int r = 0; r < 8; ++r) {
                const float xv = xs[r0 + r][k];
                acc[r][0] = fmaf(xv, w4.x, acc[r][0]);
                acc[r][1] = fmaf(xv, w4.y, acc[r][1]);
                acc[r][2] = fmaf(xv, w4.z, acc[r][2]);
                acc[r][3] = fmaf(xv, w4.w, acc[r][3]);
            }
        }
    }

#pragma unroll
    for (int r = 0; r < 8; ++r) {
        const int row = block_row + r0 + r;
        if (row < N_NODES)
            *(float4*)(hout + (size_t)row * HID + cg) =
                make_float4(acc[r][0], acc[r][1], acc[r][2], acc[r][3]);
    }
}

// ---------------- aggregation: gather over CSR, one wave per dst node ----------------
__global__ __launch_bounds__(256) void agg_csr_kernel(const int* __restrict__ row_start,
                                                      const float2* __restrict__ csr_sw,
                                                      const float* __restrict__ h,
                                                      const float* __restrict__ dinv,
                                                      const float* __restrict__ bias,
                                                      float* __restrict__ agg) {
    const int node = blockIdx.x * 4 + (threadIdx.x >> 6);
    if (node >= N_NODES) return;
    const int lane = threadIdx.x & 63;
    const int c = lane * 2;
    const int beg = row_start[node];
    const int end = row_start[node + 1];

    const float dv = dinv[node];
    const float sn = dv * dv;
    const float2 hv = *(const float2*)(h + (size_t)node * HID + c);
    const float2 bv = *(const float2*)(bias + c);
    float2 a0 = make_float2(fmaf(hv.x, sn, bv.x), fmaf(hv.y, sn, bv.y));
    float2 a1 = make_float2(0.f, 0.f);
    float2 a2 = make_float2(0.f, 0.f);
    float2 a3 = make_float2(0.f, 0.f);

    int p = beg;
    for (; p + 4 <= end; p += 4) {
        const float2 e0 = csr_sw[p];
        const float2 e1 = csr_sw[p + 1];
        const float2 e2 = csr_sw[p + 2];
        const float2 e3 = csr_sw[p + 3];
        const float2 v0 = *(const float2*)(h + (size_t)__float_as_int(e0.x) * HID + c);
        const float2 v1 = *(const float2*)(h + (size_t)__float_as_int(e1.x) * HID + c);
        const float2 v2 = *(const float2*)(h + (size_t)__float_as_int(e2.x) * HID + c);
        const float2 v3 = *(const float2*)(h + (size_t)__float_as_int(e3.x) * HID + c);
        a0.x = fmaf(v0.x, e0.y, a0.x); a0.y = fmaf(v0.y, e0.y, a0.y);
        a1.x = fmaf(v1.x, e1.y, a1.x); a1.y = fmaf(v1.y, e1.y, a1.y);
        a2.x = fmaf(v2.x, e2.y, a2.x); a2.y = fmaf(v2.y, e2.y, a2.y);
        a3.x = fmaf(v3.x, e3.y, a3.x); a3.y = fmaf(v3.y, e3.y, a3.y);
    }
    for (; p < end; ++p) {
        const float2 e0 = csr_sw[p];
        const float2 v0 = *(const float2*)(h + (size_t)__float_as_int(e0.x) * HID + c);
        a0.x = fmaf(v0.x, e0.y, a0.x); a0.y = fmaf(v0.y, e0.y, a0.y);
    }
    a0.x += (a1.x + a2.x) + a3.x;
    a0.y += (a1.y + a2.y) + a3.y;
    *(float2*)(agg + (size_t)node * HID + c) = a0;
}

// ---------------- batch-norm stats ----------------
__global__ __launch_bounds__(256) void bn_stats_kernel(const float* __restrict__ a,
                                                       float* __restrict__ stats) {
    const int c = threadIdx.x & 127;
    const int half = threadIdx.x >> 7;
    const int row0 = blockIdx.x * 128;
    int rend = row0 + 128;
    if (rend > N_NODES) rend = N_NODES;
    float s = 0.f, sq = 0.f;
    for (int r = row0 + half; r < rend; r += 2) {
        const float v = a[(size_t)r * HID + c];
        s += v;
        sq = fmaf(v, v, sq);
    }
    __shared__ float sh[2][2][128];
    sh[0][half][c] = s;
    sh[1][half][c] = sq;
    __syncthreads();
    if (half == 0) {
        atomicAdd(&stats[c], sh[0][0][c] + sh[0][1][c]);
        atomicAdd(&stats[HID + c], sh[1][0][c] + sh[1][1][c]);
    }
}

__global__ __launch_bounds__(128) void bn_fin_kernel(float* __restrict__ stats,
                                                     const float* __restrict__ gamma,
                                                     const float* __restrict__ beta) {
    const int c = threadIdx.x;
    const float invN = 1.0f / (float)N_NODES;
    const float mu = stats[c] * invN;
    const float var = stats[HID + c] * invN - mu * mu;
    const float scale = rsqrtf(var + BN_EPS) * gamma[c];
    stats[c] = scale;
    stats[HID + c] = fmaf(-mu, scale, beta[c]);
}

// ---------------- pooling: segmented (batch is sorted) ----------------
__global__ __launch_bounds__(256) void pool_seg_kernel(const float* __restrict__ a,
                                                       const int* __restrict__ bound,
                                                       float* __restrict__ z) {
    const int g = blockIdx.x;
    const int cl = threadIdx.x & 31;
    const int c = blockIdx.y * 32 + cl;
    const int par = threadIdx.x >> 5;
    const int beg = bound[g], end = bound[g + 1];
    float s = 0.f, m = 0.f;
    for (int r = beg + par; r < end; r += 8) {
        const float v = fmaxf(a[(size_t)r * HID + c], 0.f);   // layer-4 ReLU fused
        s += v;
        m = fmaxf(m, v);
    }
    __shared__ float ssum[8][32];
    __shared__ float smax[8][32];
    ssum[par][cl] = s;
    smax[par][cl] = m;
    __syncthreads();
    if (par == 0) {
        float ts = 0.f, tm = 0.f;
#pragma unroll
        for (int p = 0; p < 8; ++p) { ts += ssum[p][cl]; tm = fmaxf(tm, smax[p][cl]); }
        const float cntf = (float)(end - beg);
        z[g * 256 + c] = ts / fmaxf(cntf, 1.f);
        z[g * 256 + 128 + c] = tm;
    }
}

// ---------------- head ----------------
__global__ __launch_bounds__(128) void head_kernel(const float* __restrict__ z,
                                                   const float* __restrict__ lw1,
                                                   const float* __restrict__ lb1,
                                                   const float* __restrict__ lw2,
                                                   const float* __restrict__ lb2,
                                                   float* __restrict__ out) {
    __shared__ float zin[256];
    __shared__ float z1[128];
    const int g = blockIdx.x;
    const int t = threadIdx.x;
    zin[t] = z[g * 256 + t];
    zin[128 + t] = z[g * 256 + 128 + t];
    __syncthreads();
    float accv = lb1[t];
#pragma unroll 4
    for (int k = 0; k < 256; ++k) accv = fmaf(zin[k], lw1[k * 128 + t], accv);
    z1[t] = fmaxf(accv, 0.f);
    __syncthreads();
    if (t < 10) {
        float o = lb2[t];
#pragma unroll 4
        for (int k = 0; k < 128; ++k) o = fmaf(z1[k], lw2[k * 10 + t], o);
        out[g * 10 + t] = o;
    }
}

// ---------------- launch ----------------
extern "C" void kernel_launch(void* const* d_in, const int* in_sizes, int n_in,
                              void* d_out, int out_size, void* d_ws, size_t ws_size,
                              hipStream_t stream) {
    const float* x     = (const float*)d_in[0];
    const int*   ei    = (const int*)d_in[1];
    const int*   batch = (const int*)d_in[2];
    const float* W[4]  = {(const float*)d_in[3], (const float*)d_in[5],
                          (const float*)d_in[7], (const float*)d_in[9]};
    const float* B[4]  = {(const float*)d_in[4], (const float*)d_in[6],
                          (const float*)d_in[8], (const float*)d_in[10]};
    const float* Gm[3] = {(const float*)d_in[11], (const float*)d_in[13],
                          (const float*)d_in[15]};
    const float* Be[3] = {(const float*)d_in[12], (const float*)d_in[14],
                          (const float*)d_in[16]};
    const float* lw1 = (const float*)d_in[17];
    const float* lb1 = (const float*)d_in[18];
    const float* lw2 = (const float*)d_in[19];
    const float* lb2 = (const float*)d_in[20];

    char* ws = (char*)d_ws;
    float*  dinv      = (float*)ws;                          // @0        len 50000
    float*  stats     = (float*)(ws + 50000u * 4);           // @50000    len 256
    float*  z         = (float*)(ws + 50256u * 4);           // @50256    len 16384
    int*    degi      = (int*)  (ws + 66640u * 4);           // @66640    len 50000
    int*    cursor    = (int*)  (ws + 116640u * 4);          // @116640   len 50000
    int*    row_start = (int*)  (ws + 166640u * 4);          // @166640   len 50001
    int*    bound     = (int*)  (ws + 216644u * 4);          // @216644   len 65
    float2* csr_sw    = (float2*)(ws + 216712u * 4);         // @216712   len 2*800000 (8B-aligned)
    float*  hbuf      = (float*)(ws + 1816712u * 4);         // @1816712  len 6.4M
    float*  abuf      = (float*)(ws + 8216712u * 4);         // @8216712  len 6.4M
    int*    partials  = (int*)  (ws + 14616712u * 4);        // @14616712 len 128

    // ---- CSR build (once per launch) ----
    hipMemsetAsync(degi, 0, 100000u * sizeof(int), stream);   // degi + cursor contiguous
    deg_counti_kernel<<<(N_EDGES + 255) / 256, 256, 0, stream>>>(ei, degi);
    deg_fin_kernel<<<(N_NODES + 255) / 256, 256, 0, stream>>>(degi, dinv);
    scan1_kernel<<<SCAN_B, 512, 0, stream>>>(degi, row_start, partials);
    scan2_kernel<<<1, 128, 0, stream>>>(partials, row_start);
    scan3_kernel<<<SCAN_B, 512, 0, stream>>>(row_start, partials);
    scatter_kernel<<<(N_EDGES + 255) / 256, 256, 0, stream>>>(ei, dinv, row_start,
                                                              cursor, csr_sw);
    bounds_kernel<<<(N_NODES + 255) / 256, 256, 0, stream>>>(batch, bound);

    // ---- layers ----
    const float* cur = x;
    for (int l = 0; l < 4; ++l) {
        gemm_kernel<<<(N_NODES + 63) / 64, 256, 0, stream>>>(cur, W[l], stats,
                                                             l > 0 ? 1 : 0, hbuf);
        agg_csr_kernel<<<(N_NODES + 3) / 4, 256, 0, stream>>>(row_start, csr_sw, hbuf,
                                                              dinv, B[l], abuf);
        if (l < 3) {
            hipMemsetAsync(stats, 0, 256 * sizeof(float), stream);
            bn_stats_kernel<<<(N_NODES + 127) / 128, 256, 0, stream>>>(abuf, stats);
            bn_fin_kernel<<<1, 128, 0, stream>>>(stats, Gm[l], Be[l]);
        }
        cur = abuf;
    }

    // ---- pooling + head ----
    pool_seg_kernel<<<dim3(NGRAPH, 4), 256, 0, stream>>>(abuf, bound, z);
    head_kernel<<<NGRAPH, 128, 0, stream>>>(z, lw1, lb1, lw2, lb2, (float*)d_out);
}